// Round 9
// baseline (253.825 us; speedup 1.0000x reference)
//
#include <hip/hip_runtime.h>

constexpr int NN = 100000;   // nodes (= 3125 * 32 exactly)
constexpr int NE = 1600000;  // edges
constexpr int DD = 64;       // channels
constexpr int NG = 256;      // graphs

constexpr int BKT_SHIFT = 8;                   // 256 nodes per bucket
constexpr int NBKT = (NN + 255) >> BKT_SHIFT;  // 391 buckets
constexpr int EPB = 4096;                      // edges per pscat chunk
constexpr int NEB = (NE + EPB - 1) / EPB;      // 391 chunks
constexpr int CAP = 6144;                      // per-bucket csr window (mean 4096, +32 sigma)
constexpr int XCB = NN * 16 / 256;             // 6250 xconv work blocks

using bf16x8 = __attribute__((ext_vector_type(8))) short;
using f32x4 = __attribute__((ext_vector_type(4))) float;

// ---------------------------------------------------------------------------
// bf16 helpers (manual, RNE)
// ---------------------------------------------------------------------------
__device__ __forceinline__ float b2f(unsigned short u) {
    union { unsigned int u; float f; } c;
    c.u = ((unsigned int)u) << 16;
    return c.f;
}
__device__ __forceinline__ unsigned short f2b(float f) {
    union { float f; unsigned int u; } c;
    c.f = f;
    unsigned int u = c.u + 0x7fff + ((c.u >> 16) & 1);
    return (unsigned short)(u >> 16);
}
__device__ __forceinline__ float lo16(unsigned int u) {
    union { unsigned int u; float f; } c;
    c.u = u << 16;
    return c.f;
}
__device__ __forceinline__ float hi16(unsigned int u) {
    union { unsigned int u; float f; } c;
    c.u = u & 0xffff0000u;
    return c.f;
}
__device__ __forceinline__ unsigned int pk(float a, float b) {
    return ((unsigned int)f2b(a)) | (((unsigned int)f2b(b)) << 16);
}

__device__ __forceinline__ void xconv(const float* __restrict__ x,
                                      unsigned short* __restrict__ xb, int i) {
    float4 v = reinterpret_cast<const float4*>(x)[i];
    ushort4 o;
    o.x = f2b(v.x); o.y = f2b(v.y); o.z = f2b(v.z); o.w = f2b(v.w);
    reinterpret_cast<ushort4*>(xb)[i] = o;
}

__device__ __forceinline__ void wconv(const float* __restrict__ w,
                                      unsigned short* __restrict__ o, int tid) {
    for (int i = tid; i < 4096; i += 256) {
        int j = i & 7;
        int quad = (i >> 3) & 3;
        int n = (i >> 5) & 63;
        int kb = i >> 11;
        int k = kb * 32 + quad * 8 + j;
        float wv = w[k * 64 + n];
        unsigned short hi = f2b(wv);
        o[i] = hi;
        o[i + 4096] = f2b(wv - b2f(hi));
    }
}

// exclusive scan of v across 256 threads (all threads must call); total = incl[255]
__device__ __forceinline__ int scan256_excl(int v, int* sh, int tid, int& total) {
    __syncthreads();
    sh[tid] = v;
    __syncthreads();
    for (int off = 1; off < 256; off <<= 1) {
        int u = (tid >= off) ? sh[tid - off] : 0;
        __syncthreads();
        sh[tid] += u;
        __syncthreads();
    }
    total = sh[255];
    return sh[tid] - v;
}

// ---------------------------------------------------------------------------
// build1_k (verified round-5): pscat chunks + wconv + out-init + xconv.
// [round-1 lesson: 1.6M per-node global atomics = 143 us; keep LDS-aggregated]
// [round-3 lesson: cooperative grid.sync = 3x regression on gfx950; never]
// [round-4 lesson: barrier REQUIRED between LDS atomic count loop and scan]
// ---------------------------------------------------------------------------
__global__ __launch_bounds__(256) void build1_k(
    const int* __restrict__ ei, int* __restrict__ pairs, int* __restrict__ ocnt,
    const float* __restrict__ x, unsigned short* __restrict__ xb,
    const float* __restrict__ w0, const float* __restrict__ w1,
    const float* __restrict__ w2, const float* __restrict__ w3,
    const float* __restrict__ w4, const float* __restrict__ w5,
    unsigned short* __restrict__ wf, const float* __restrict__ fcb,
    float* __restrict__ outp) {
    int bid = blockIdx.x;
    int tid = threadIdx.x;
    if (bid >= NEB) {
        int r = bid - NEB;
        if (r < 6) {
            const float* ws[6] = {w0, w1, w2, w3, w4, w5};
            wconv(ws[r], wf + r * 8192, tid);
        } else if (r == 6) {
            if (tid < NG) outp[tid] = fcb[0];
        } else {
            xconv(x, xb, (r - 7) * 256 + tid);
        }
        return;
    }
    __shared__ int cntl[NBKT];
    __shared__ int loff[NBKT];
    __shared__ int lcur[NBKT];
    __shared__ int sh[256];
    int j = bid;
    int base = j * EPB;
    int n = min(base + EPB, NE) - base;
    for (int i = tid; i < NBKT; i += 256) cntl[i] = 0;
    __syncthreads();
    for (int t = tid; t < n; t += 256) {
        int dst = ei[NE + base + t];
        atomicAdd(&cntl[dst >> BKT_SHIFT], 1);
    }
    __syncthreads();  // ALL counts visible before scan reads (round-4 bug fix)
    int e0 = 2 * tid, e1 = 2 * tid + 1;
    int c0 = (e0 < NBKT) ? cntl[e0] : 0;
    int c1 = (e1 < NBKT) ? cntl[e1] : 0;
    int tot;
    int ex = scan256_excl(c0 + c1, sh, tid, tot);
    if (e0 < NBKT) loff[e0] = ex;
    if (e1 < NBKT) loff[e1] = ex + c0;
    __syncthreads();
    for (int i = tid; i < NBKT; i += 256) {
        ocnt[j * NBKT + i] = (loff[i] << 16) | cntl[i];
        lcur[i] = 0;
    }
    __syncthreads();
    for (int t = tid; t < n; t += 256) {
        int src = ei[base + t];
        int dst = ei[NE + base + t];
        int b = dst >> BKT_SHIFT;
        int pos = loff[b] + atomicAdd(&lcur[b], 1);
        pairs[j * EPB + pos] = src | ((dst & 255) << 17);
    }
}

// ---------------------------------------------------------------------------
// build2_k (verified round-5): bucket gather + per-node counting sort.
// ---------------------------------------------------------------------------
__global__ __launch_bounds__(256) void build2_k(
    const int* __restrict__ pairs, const int* __restrict__ ocnt,
    int* __restrict__ rowptr, int* __restrict__ degs, int* __restrict__ csr) {
    __shared__ int stag[CAP];
    __shared__ int pb_[NBKT];
    __shared__ int po_[NBKT];
    __shared__ int pc_[NBKT];
    __shared__ int sh[256];
    __shared__ int ldeg[256];
    __shared__ int lcur[256];
    int b = blockIdx.x;
    int tid = threadIdx.x;
    int e0 = 2 * tid, e1 = 2 * tid + 1;
    int o0 = 0, c0 = 0, o1 = 0, c1 = 0;
    if (e0 < NBKT) { int v = ocnt[e0 * NBKT + b]; o0 = v >> 16; c0 = v & 0xffff; }
    if (e1 < NBKT) { int v = ocnt[e1 * NBKT + b]; o1 = v >> 16; c1 = v & 0xffff; }
    int tot;
    int ex = scan256_excl(c0 + c1, sh, tid, tot);
    if (e0 < NBKT) { pb_[e0] = ex; po_[e0] = o0; pc_[e0] = c0; }
    if (e1 < NBKT) { pb_[e1] = ex + c0; po_[e1] = o1; pc_[e1] = c1; }
    ldeg[tid] = 0;
    __syncthreads();
    int pcnt = min(tot, CAP);
    for (int j = tid; j < NBKT; j += 256) {
        int d = pb_[j], pc = pc_[j];
        const int* src = pairs + j * EPB + po_[j];
        for (int k = 0; k < pc; ++k) {
            int dd = d + k;
            if (dd < CAP) stag[dd] = src[k];
        }
    }
    __syncthreads();
    for (int i = tid; i < pcnt; i += 256)
        atomicAdd(&ldeg[(stag[i] >> 17) & 255], 1);
    __syncthreads();
    int v = ldeg[tid];
    int tot2;
    int lexcl = scan256_excl(v, sh, tid, tot2);
    int node = (b << BKT_SHIFT) + tid;
    if (node < NN) {
        rowptr[node] = b * CAP + lexcl;
        degs[node] = v;
    }
    lcur[tid] = lexcl;
    __syncthreads();
    for (int i = tid; i < pcnt; i += 256) {
        int p = stag[i];
        int pos = atomicAdd(&lcur[(p >> 17) & 255], 1);
        csr[b * CAP + pos] = p & 0x1FFFF;
    }
}

// ---------------------------------------------------------------------------
// Fused GIN layer. Phase A: depth-8 VGPR-ring gather, uniform lookahead 6
// (every step consumed exactly 6 issues after its own issue). Unroll-8 body;
// 8|8 so ring slots are loop-invariant compile-time constants (rule #20).
// [round-8 evidence: depth-4 ring cut gin 46.5->~39 us; VGPR headroom to 64]
// [round-7 lesson: no LDS staging — pipeline in VGPRs]
// 0-padded indices make all tail/overshoot issues benign row-0 loads.
// ---------------------------------------------------------------------------
__global__ __launch_bounds__(256) void gin_k(
    const uint4* __restrict__ hb4,     // prev h (bf16): gather + self source
    const float4* __restrict__ selff,  // fp32 self (layer 0) or null
    const int* __restrict__ rowptr, const int* __restrict__ degv,
    const int* __restrict__ csr_src,
    const unsigned short* __restrict__ wf1, const float* __restrict__ b1,
    const unsigned short* __restrict__ wf2, const float* __restrict__ b2,
    unsigned short* __restrict__ houtb, int relu_out, int pool_mode,
    const int* __restrict__ batch, const float* __restrict__ fcw,
    float* __restrict__ outp) {
    __shared__ unsigned short zl[32 * 72];   // z tile (bf16)
    __shared__ unsigned short hlh[32 * 72];  // h1 hi
    __shared__ unsigned short hll[32 * 72];  // h1 lo
    int tid = threadIdx.x;
    int lane = tid & 63;
    int wv = tid >> 6;
    int base = blockIdx.x * 32;

    // ---- Phase A: depth-8 pipelined gather + self -> zl ----
    {
        int nl = lane >> 3;  // node slot within wave (0..7)
        int c = lane & 7;    // 16 B chunk within row (0..7)
        int r = wv * 8 + nl; // local row 0..31
        int node = base + r;
        int beg = rowptr[node];
        int deg = degv[node];
        float a0 = 0, a1 = 0, a2 = 0, a3 = 0, a4 = 0, a5 = 0, a6 = 0, a7 = 0;
        int nb = (deg + 7) >> 3;
        int nbm = nb;
#pragma unroll
        for (int off = 32; off > 0; off >>= 1) {
            int o = __shfl_xor(nbm, off, 64);
            nbm = max(nbm, o);
        }
        int steps = nbm << 3;  // uniform per wave; multiple of 8
        int gbase = nl << 3;
        int idxc = (c < deg) ? csr_src[beg + c] : 0;          // block k/8 srcs
        int idxn = (8 + c < deg) ? csr_src[beg + 8 + c] : 0;  // next block

        if (steps > 0) {
            uint4 v0, v1, v2, v3, v4, v5, v6, v7;
#define GIN_ISSUE(REG, LN)                                        \
    {                                                             \
        int sv = __shfl(idxc, gbase + (LN), 64);                  \
        REG = hb4[(size_t)sv * 8 + c];                            \
    }
#define GIN_CONS(REG, EO)                                         \
    if (e + (EO) < deg) {                                         \
        a0 += lo16(REG.x); a1 += hi16(REG.x);                     \
        a2 += lo16(REG.y); a3 += hi16(REG.y);                     \
        a4 += lo16(REG.z); a5 += hi16(REG.z);                     \
        a6 += lo16(REG.w); a7 += hi16(REG.w);                     \
    }
            // prologue: k = 0..5 -> slots 0..5 (all block 0; 0-padded idx)
            GIN_ISSUE(v0, 0)
            GIN_ISSUE(v1, 1)
            GIN_ISSUE(v2, 2)
            GIN_ISSUE(v3, 3)
            GIN_ISSUE(v4, 4)
            GIN_ISSUE(v5, 5)
            for (int e = 0; e < steps; e += 8) {
                // invariant: v0..v5 hold steps e..e+5; idxc=block(e/8),
                // idxn=block(e/8+1)
                GIN_ISSUE(v6, 6) GIN_CONS(v0, 0)   // issue k=e+6
                GIN_ISSUE(v7, 7) GIN_CONS(v1, 1)   // k=e+7
                idxc = idxn;                        // cross to block(e/8+1)
                {
                    int nj = e + 16 + c;            // prefetch block(e/8+2)
                    idxn = (nj < deg) ? csr_src[beg + nj] : 0;
                }
                GIN_ISSUE(v0, 0) GIN_CONS(v2, 2)   // k=e+8
                GIN_ISSUE(v1, 1) GIN_CONS(v3, 3)   // k=e+9
                GIN_ISSUE(v2, 2) GIN_CONS(v4, 4)   // k=e+10
                GIN_ISSUE(v3, 3) GIN_CONS(v5, 5)   // k=e+11
                GIN_ISSUE(v4, 4) GIN_CONS(v6, 6)   // k=e+12
                GIN_ISSUE(v5, 5) GIN_CONS(v7, 7)   // k=e+13
            }
#undef GIN_ISSUE
#undef GIN_CONS
            // v0..v5 hold 6 tail dummies (row 0); compiler waits before reuse
        }
        if (selff) {
            float4 s0 = selff[(size_t)node * 16 + 2 * c];
            float4 s1 = selff[(size_t)node * 16 + 2 * c + 1];
            a0 += s0.x; a1 += s0.y; a2 += s0.z; a3 += s0.w;
            a4 += s1.x; a5 += s1.y; a6 += s1.z; a7 += s1.w;
        } else {
            uint4 sv = hb4[node * 8 + c];
            a0 += lo16(sv.x); a1 += hi16(sv.x);
            a2 += lo16(sv.y); a3 += hi16(sv.y);
            a4 += lo16(sv.z); a5 += hi16(sv.z);
            a6 += lo16(sv.w); a7 += hi16(sv.w);
        }
        uint4 o;
        o.x = pk(a0, a1); o.y = pk(a2, a3); o.z = pk(a4, a5); o.w = pk(a6, a7);
        *reinterpret_cast<uint4*>(&zl[r * 72 + c * 8]) = o;
    }
    __syncthreads();

    // ---- Phase B: MLP on the 32-row tile (verified round-5 body) ----
    int m = lane & 15;
    int quad = lane >> 4;
    int mt = wv >> 1;  // row half (rows mt*16 + 0..15)
    int nh = wv & 1;   // col half (n-tiles nh*2, nh*2+1)
    int lrow = mt * 16 + m;

    bf16x8 a0 = *reinterpret_cast<const bf16x8*>(&zl[lrow * 72 + quad * 8]);
    bf16x8 a1 = *reinterpret_cast<const bf16x8*>(&zl[lrow * 72 + 32 + quad * 8]);
    const bf16x8* wh1 = reinterpret_cast<const bf16x8*>(wf1);
    const bf16x8* wl1 = reinterpret_cast<const bf16x8*>(wf1 + 4096);
    f32x4 acc[2];
#pragma unroll
    for (int nt2 = 0; nt2 < 2; ++nt2) {
        int n = (nh * 2 + nt2) * 16 + m;
        bf16x8 bh0 = wh1[(0 * 64 + n) * 4 + quad];
        bf16x8 bh1 = wh1[(1 * 64 + n) * 4 + quad];
        bf16x8 bl0 = wl1[(0 * 64 + n) * 4 + quad];
        bf16x8 bl1 = wl1[(1 * 64 + n) * 4 + quad];
        f32x4 c = {0.f, 0.f, 0.f, 0.f};
        c = __builtin_amdgcn_mfma_f32_16x16x32_bf16(a0, bh0, c, 0, 0, 0);
        c = __builtin_amdgcn_mfma_f32_16x16x32_bf16(a1, bh1, c, 0, 0, 0);
        c = __builtin_amdgcn_mfma_f32_16x16x32_bf16(a0, bl0, c, 0, 0, 0);
        c = __builtin_amdgcn_mfma_f32_16x16x32_bf16(a1, bl1, c, 0, 0, 0);
        acc[nt2] = c;
    }
    // h1 = ReLU(acc + b1) -> split bf16 into LDS (C-layout scatter)
#pragma unroll
    for (int nt2 = 0; nt2 < 2; ++nt2) {
        int col = (nh * 2 + nt2) * 16 + m;
        float bb = b1[col];
#pragma unroll
        for (int rr = 0; rr < 4; ++rr) {
            float v = fmaxf(acc[nt2][rr] + bb, 0.f);
            unsigned short hi = f2b(v);
            hlh[(mt * 16 + quad * 4 + rr) * 72 + col] = hi;
            hll[(mt * 16 + quad * 4 + rr) * 72 + col] = f2b(v - b2f(hi));
        }
    }
    __syncthreads();

    // GEMM2: A (hi+lo) from LDS
    bf16x8 ch0 = *reinterpret_cast<const bf16x8*>(&hlh[lrow * 72 + quad * 8]);
    bf16x8 ch1 = *reinterpret_cast<const bf16x8*>(&hlh[lrow * 72 + 32 + quad * 8]);
    bf16x8 cl0 = *reinterpret_cast<const bf16x8*>(&hll[lrow * 72 + quad * 8]);
    bf16x8 cl1 = *reinterpret_cast<const bf16x8*>(&hll[lrow * 72 + 32 + quad * 8]);
    const bf16x8* wh2 = reinterpret_cast<const bf16x8*>(wf2);
    const bf16x8* wl2 = reinterpret_cast<const bf16x8*>(wf2 + 4096);
#pragma unroll
    for (int nt2 = 0; nt2 < 2; ++nt2) {
        int n = (nh * 2 + nt2) * 16 + m;
        bf16x8 bh0 = wh2[(0 * 64 + n) * 4 + quad];
        bf16x8 bh1 = wh2[(1 * 64 + n) * 4 + quad];
        bf16x8 bl0 = wl2[(0 * 64 + n) * 4 + quad];
        bf16x8 bl1 = wl2[(1 * 64 + n) * 4 + quad];
        f32x4 c = {0.f, 0.f, 0.f, 0.f};
        c = __builtin_amdgcn_mfma_f32_16x16x32_bf16(ch0, bh0, c, 0, 0, 0);
        c = __builtin_amdgcn_mfma_f32_16x16x32_bf16(ch1, bh1, c, 0, 0, 0);
        c = __builtin_amdgcn_mfma_f32_16x16x32_bf16(ch0, bl0, c, 0, 0, 0);
        c = __builtin_amdgcn_mfma_f32_16x16x32_bf16(ch1, bl1, c, 0, 0, 0);
        c = __builtin_amdgcn_mfma_f32_16x16x32_bf16(cl0, bh0, c, 0, 0, 0);
        c = __builtin_amdgcn_mfma_f32_16x16x32_bf16(cl1, bh1, c, 0, 0, 0);
        acc[nt2] = c;
    }
    __syncthreads();  // all GEMM2 LDS reads done; hlh/hll reusable

    if (pool_mode) {
        // fused global_add_pool + FC
        float psum[4] = {0.f, 0.f, 0.f, 0.f};
#pragma unroll
        for (int nt2 = 0; nt2 < 2; ++nt2) {
            int col = (nh * 2 + nt2) * 16 + m;
            float fw = fcw[col];
            float bb = b2[col];
#pragma unroll
            for (int rr = 0; rr < 4; ++rr) psum[rr] += (acc[nt2][rr] + bb) * fw;
        }
#pragma unroll
        for (int rr = 0; rr < 4; ++rr)
#pragma unroll
            for (int off = 8; off > 0; off >>= 1)
                psum[rr] += __shfl_down(psum[rr], off, 64);
        float* gsum = reinterpret_cast<float*>(hlh);
        gsum[tid] = 0.f;  // tid 0..255 == graph ids
        __syncthreads();
        if (m == 0) {
#pragma unroll
            for (int rr = 0; rr < 4; ++rr) {
                int row = base + mt * 16 + quad * 4 + rr;
                atomicAdd(&gsum[batch[row]], psum[rr]);
            }
        }
        __syncthreads();
        float v = gsum[tid];
        if (v != 0.f) unsafeAtomicAdd(&outp[tid], v);
        return;
    }

    // epilogue: bias (+relu) -> LDS bf16, then coalesced stores
#pragma unroll
    for (int nt2 = 0; nt2 < 2; ++nt2) {
        int col = (nh * 2 + nt2) * 16 + m;
        float bb = b2[col];
#pragma unroll
        for (int rr = 0; rr < 4; ++rr) {
            float v = acc[nt2][rr] + bb;
            if (relu_out) v = fmaxf(v, 0.f);
            hlh[(mt * 16 + quad * 4 + rr) * 72 + col] = f2b(v);
        }
    }
    __syncthreads();
    {
        int row = tid >> 3;  // 0..31
        int ch = tid & 7;
        uint4 v = *reinterpret_cast<const uint4*>(&hlh[row * 72 + ch * 8]);
        *reinterpret_cast<uint4*>(houtb + (size_t)(base + row) * 64 + ch * 8) = v;
    }
}

extern "C" void kernel_launch(void* const* d_in, const int* in_sizes, int n_in,
                              void* d_out, int out_size, void* d_ws, size_t ws_size,
                              hipStream_t stream) {
    const float* x = (const float*)d_in[0];
    const int* ei = (const int*)d_in[1];     // [2, E] flat
    const int* batch = (const int*)d_in[2];  // [N], sorted
    const float* w[3][4];
    for (int l = 0; l < 3; ++l)
        for (int i = 0; i < 4; ++i) w[l][i] = (const float*)d_in[3 + l * 4 + i];
    const float* fcw = (const float*)d_in[15];
    const float* fcb = (const float*)d_in[16];
    float* out = (float*)d_out;

    // workspace layout (~43 MB), every region 256 B aligned
    char* wsb = (char*)d_ws;
    size_t o = 0;
    auto carve = [&](size_t bytes) {
        char* p = wsb + o;
        o += (bytes + 255) & ~(size_t)255;
        return p;
    };
    int* pairs = (int*)carve((size_t)NEB * EPB * 4);       // 6.4 MB
    int* ocnt = (int*)carve((size_t)NEB * NBKT * 4);       // 0.6 MB
    int* csr = (int*)carve((size_t)NBKT * CAP * 4);        // 9.6 MB
    int* rowptr = (int*)carve((size_t)NN * 4);
    int* degs = (int*)carve((size_t)NN * 4);
    unsigned short* H0 = (unsigned short*)carve((size_t)NN * DD * 2);  // 12.8 MB
    unsigned short* H1 = (unsigned short*)carve((size_t)NN * DD * 2);  // 12.8 MB
    unsigned short* wf = (unsigned short*)carve(6 * 8192 * 2);

    // D1: pscat (no-atomic count matrix) + wconv + out-init + xconv
    build1_k<<<NEB + 7 + XCB, 256, 0, stream>>>(ei, pairs, ocnt, x, H0, w[0][0],
                                                w[0][2], w[1][0], w[1][2],
                                                w[2][0], w[2][2], wf, fcb, out);
    // D2: bucket gather + per-node counting sort -> csr/rowptr/degs
    build2_k<<<NBKT, 256, 0, stream>>>(pairs, ocnt, rowptr, degs, csr);

    dim3 lgrid(NN / 32);
    // D3 L0: read H0(=xb)+x, write H1
    gin_k<<<lgrid, 256, 0, stream>>>((const uint4*)H0, (const float4*)x, rowptr,
                                     degs, csr, wf + 0 * 8192, w[0][1],
                                     wf + 1 * 8192, w[0][3], H1, 1, 0, nullptr,
                                     nullptr, nullptr);
    // D4 L1: read H1, write H0
    gin_k<<<lgrid, 256, 0, stream>>>((const uint4*)H1, nullptr, rowptr, degs,
                                     csr, wf + 2 * 8192, w[1][1], wf + 3 * 8192,
                                     w[1][3], H0, 1, 0, nullptr, nullptr,
                                     nullptr);
    // D5 L2: read H0, fused pool + FC
    gin_k<<<lgrid, 256, 0, stream>>>((const uint4*)H0, nullptr, rowptr, degs,
                                     csr, wf + 4 * 8192, w[2][1], wf + 5 * 8192,
                                     w[2][3], nullptr, 0, 1, batch, fcw, out);
}

// Round 10
// 252.490 us; speedup vs baseline: 1.0053x; 1.0053x over previous
//
#include <hip/hip_runtime.h>

constexpr int NN = 100000;   // nodes (= 3125 * 32 exactly)
constexpr int NE = 1600000;  // edges
constexpr int DD = 64;       // channels
constexpr int NG = 256;      // graphs

constexpr int BKT_SHIFT = 8;                   // 256 nodes per bucket
constexpr int NBKT = (NN + 255) >> BKT_SHIFT;  // 391 buckets
constexpr int EPB = 4096;                      // edges per pscat chunk
constexpr int NEB = (NE + EPB - 1) / EPB;      // 391 chunks
constexpr int CAP = 6144;                      // per-bucket csr window (mean 4096, +32 sigma)
constexpr int XCB = NN * 16 / 256;             // 6250 xconv work blocks

using bf16x8 = __attribute__((ext_vector_type(8))) short;
using f32x4 = __attribute__((ext_vector_type(4))) float;

// ---------------------------------------------------------------------------
// bf16 helpers (manual, RNE)
// ---------------------------------------------------------------------------
__device__ __forceinline__ float b2f(unsigned short u) {
    union { unsigned int u; float f; } c;
    c.u = ((unsigned int)u) << 16;
    return c.f;
}
__device__ __forceinline__ unsigned short f2b(float f) {
    union { float f; unsigned int u; } c;
    c.f = f;
    unsigned int u = c.u + 0x7fff + ((c.u >> 16) & 1);
    return (unsigned short)(u >> 16);
}
__device__ __forceinline__ float lo16(unsigned int u) {
    union { unsigned int u; float f; } c;
    c.u = u << 16;
    return c.f;
}
__device__ __forceinline__ float hi16(unsigned int u) {
    union { unsigned int u; float f; } c;
    c.u = u & 0xffff0000u;
    return c.f;
}
__device__ __forceinline__ unsigned int pk(float a, float b) {
    return ((unsigned int)f2b(a)) | (((unsigned int)f2b(b)) << 16);
}

__device__ __forceinline__ void xconv(const float* __restrict__ x,
                                      unsigned short* __restrict__ xb, int i) {
    float4 v = reinterpret_cast<const float4*>(x)[i];
    ushort4 o;
    o.x = f2b(v.x); o.y = f2b(v.y); o.z = f2b(v.z); o.w = f2b(v.w);
    reinterpret_cast<ushort4*>(xb)[i] = o;
}

__device__ __forceinline__ void wconv(const float* __restrict__ w,
                                      unsigned short* __restrict__ o, int tid) {
    for (int i = tid; i < 4096; i += 256) {
        int j = i & 7;
        int quad = (i >> 3) & 3;
        int n = (i >> 5) & 63;
        int kb = i >> 11;
        int k = kb * 32 + quad * 8 + j;
        float wv = w[k * 64 + n];
        unsigned short hi = f2b(wv);
        o[i] = hi;
        o[i + 4096] = f2b(wv - b2f(hi));
    }
}

// exclusive scan of v across 256 threads (all threads must call); total = incl[255]
__device__ __forceinline__ int scan256_excl(int v, int* sh, int tid, int& total) {
    __syncthreads();
    sh[tid] = v;
    __syncthreads();
    for (int off = 1; off < 256; off <<= 1) {
        int u = (tid >= off) ? sh[tid - off] : 0;
        __syncthreads();
        sh[tid] += u;
        __syncthreads();
    }
    total = sh[255];
    return sh[tid] - v;
}

// ---------------------------------------------------------------------------
// build1_k (verified round-5): pscat chunks + wconv + out-init + xconv.
// [round-1 lesson: 1.6M per-node global atomics = 143 us; keep LDS-aggregated]
// [round-3 lesson: cooperative grid.sync = 3x regression on gfx950; never]
// [round-4 lesson: barrier REQUIRED between LDS atomic count loop and scan]
// ---------------------------------------------------------------------------
__global__ __launch_bounds__(256) void build1_k(
    const int* __restrict__ ei, int* __restrict__ pairs, int* __restrict__ ocnt,
    const float* __restrict__ x, unsigned short* __restrict__ xb,
    const float* __restrict__ w0, const float* __restrict__ w1,
    const float* __restrict__ w2, const float* __restrict__ w3,
    const float* __restrict__ w4, const float* __restrict__ w5,
    unsigned short* __restrict__ wf, const float* __restrict__ fcb,
    float* __restrict__ outp) {
    int bid = blockIdx.x;
    int tid = threadIdx.x;
    if (bid >= NEB) {
        int r = bid - NEB;
        if (r < 6) {
            const float* ws[6] = {w0, w1, w2, w3, w4, w5};
            wconv(ws[r], wf + r * 8192, tid);
        } else if (r == 6) {
            if (tid < NG) outp[tid] = fcb[0];
        } else {
            xconv(x, xb, (r - 7) * 256 + tid);
        }
        return;
    }
    __shared__ int cntl[NBKT];
    __shared__ int loff[NBKT];
    __shared__ int lcur[NBKT];
    __shared__ int sh[256];
    int j = bid;
    int base = j * EPB;
    int n = min(base + EPB, NE) - base;
    for (int i = tid; i < NBKT; i += 256) cntl[i] = 0;
    __syncthreads();
    for (int t = tid; t < n; t += 256) {
        int dst = ei[NE + base + t];
        atomicAdd(&cntl[dst >> BKT_SHIFT], 1);
    }
    __syncthreads();  // ALL counts visible before scan reads (round-4 bug fix)
    int e0 = 2 * tid, e1 = 2 * tid + 1;
    int c0 = (e0 < NBKT) ? cntl[e0] : 0;
    int c1 = (e1 < NBKT) ? cntl[e1] : 0;
    int tot;
    int ex = scan256_excl(c0 + c1, sh, tid, tot);
    if (e0 < NBKT) loff[e0] = ex;
    if (e1 < NBKT) loff[e1] = ex + c0;
    __syncthreads();
    for (int i = tid; i < NBKT; i += 256) {
        ocnt[j * NBKT + i] = (loff[i] << 16) | cntl[i];
        lcur[i] = 0;
    }
    __syncthreads();
    for (int t = tid; t < n; t += 256) {
        int src = ei[base + t];
        int dst = ei[NE + base + t];
        int b = dst >> BKT_SHIFT;
        int pos = loff[b] + atomicAdd(&lcur[b], 1);
        pairs[j * EPB + pos] = src | ((dst & 255) << 17);
    }
}

// ---------------------------------------------------------------------------
// build2_k: bucket gather + per-node counting sort.
// Staging is lane-cooperative (round-10 change): 16-lane groups load each
// chunk-run coalesced, instead of one thread serially walking a whole run.
// 391 blocks = 1.5/CU — no TLP to hide serial per-thread loads, so ILP/width
// inside the block is the only lever.
// ---------------------------------------------------------------------------
__global__ __launch_bounds__(256) void build2_k(
    const int* __restrict__ pairs, const int* __restrict__ ocnt,
    int* __restrict__ rowptr, int* __restrict__ degs, int* __restrict__ csr) {
    __shared__ int stag[CAP];
    __shared__ int pb_[NBKT];
    __shared__ int po_[NBKT];
    __shared__ int pc_[NBKT];
    __shared__ int sh[256];
    __shared__ int ldeg[256];
    __shared__ int lcur[256];
    int b = blockIdx.x;
    int tid = threadIdx.x;
    int e0 = 2 * tid, e1 = 2 * tid + 1;
    int o0 = 0, c0 = 0, o1 = 0, c1 = 0;
    if (e0 < NBKT) { int v = ocnt[e0 * NBKT + b]; o0 = v >> 16; c0 = v & 0xffff; }
    if (e1 < NBKT) { int v = ocnt[e1 * NBKT + b]; o1 = v >> 16; c1 = v & 0xffff; }
    int tot;
    int ex = scan256_excl(c0 + c1, sh, tid, tot);
    if (e0 < NBKT) { pb_[e0] = ex; po_[e0] = o0; pc_[e0] = c0; }
    if (e1 < NBKT) { pb_[e1] = ex + c0; po_[e1] = o1; pc_[e1] = c1; }
    ldeg[tid] = 0;
    __syncthreads();
    int pcnt = min(tot, CAP);
    // stage runs into LDS packed — 16-lane-cooperative per chunk-run
    {
        int grp = tid >> 4;  // 0..15
        int gl = tid & 15;
        for (int j = grp; j < NBKT; j += 16) {
            int d = pb_[j], pcn = pc_[j];
            const int* src = pairs + j * EPB + po_[j];
            for (int k = gl; k < pcn; k += 16) {
                int dd = d + k;
                if (dd < CAP) stag[dd] = src[k];
            }
        }
    }
    __syncthreads();
    for (int i = tid; i < pcnt; i += 256)
        atomicAdd(&ldeg[(stag[i] >> 17) & 255], 1);
    __syncthreads();
    int v = ldeg[tid];
    int tot2;
    int lexcl = scan256_excl(v, sh, tid, tot2);
    int node = (b << BKT_SHIFT) + tid;
    if (node < NN) {
        rowptr[node] = b * CAP + lexcl;
        degs[node] = v;
    }
    lcur[tid] = lexcl;
    __syncthreads();
    for (int i = tid; i < pcnt; i += 256) {
        int p = stag[i];
        int pos = atomicAdd(&lcur[(p >> 17) & 255], 1);
        csr[b * CAP + pos] = p & 0x1FFFF;
    }
}

// ---------------------------------------------------------------------------
// Fused GIN layer. Phase A: depth-4 VGPR-ring gather (issue 3 ahead) — the
// round-8 verified body (VGPR 44, gin ~39 us).
// [round-9 lesson: depth-8 == depth-4 (253.8 vs 253.1) — gather is at the
//  random-access memory-BW floor, not latency-limited; stop deepening.]
// [round-7 lesson: no LDS staging — pipeline in VGPRs]
// Unroll-8 body: every ring index is a compile-time constant (rule #20).
// ---------------------------------------------------------------------------
__global__ __launch_bounds__(256) void gin_k(
    const uint4* __restrict__ hb4,     // prev h (bf16): gather + self source
    const float4* __restrict__ selff,  // fp32 self (layer 0) or null
    const int* __restrict__ rowptr, const int* __restrict__ degv,
    const int* __restrict__ csr_src,
    const unsigned short* __restrict__ wf1, const float* __restrict__ b1,
    const unsigned short* __restrict__ wf2, const float* __restrict__ b2,
    unsigned short* __restrict__ houtb, int relu_out, int pool_mode,
    const int* __restrict__ batch, const float* __restrict__ fcw,
    float* __restrict__ outp) {
    __shared__ unsigned short zl[32 * 72];   // z tile (bf16)
    __shared__ unsigned short hlh[32 * 72];  // h1 hi
    __shared__ unsigned short hll[32 * 72];  // h1 lo
    int tid = threadIdx.x;
    int lane = tid & 63;
    int wv = tid >> 6;
    int base = blockIdx.x * 32;

    // ---- Phase A: depth-4 pipelined gather + self -> zl ----
    {
        int nl = lane >> 3;  // node slot within wave (0..7)
        int c = lane & 7;    // 16 B chunk within row (0..7)
        int r = wv * 8 + nl; // local row 0..31
        int node = base + r;
        int beg = rowptr[node];
        int deg = degv[node];
        float a0 = 0, a1 = 0, a2 = 0, a3 = 0, a4 = 0, a5 = 0, a6 = 0, a7 = 0;
        int nb = (deg + 7) >> 3;
        int nbm = nb;
#pragma unroll
        for (int off = 32; off > 0; off >>= 1) {
            int o = __shfl_xor(nbm, off, 64);
            nbm = max(nbm, o);
        }
        int steps = nbm << 3;  // uniform per wave; multiple of 8
        int gbase = nl << 3;
        int idxc = (c < deg) ? csr_src[beg + c] : 0;          // block k/8 srcs
        int idxn = (8 + c < deg) ? csr_src[beg + 8 + c] : 0;  // next block

        if (steps > 0) {
            uint4 v0, v1, v2, v3;
#define GIN_ISSUE(REG, LN)                                        \
    {                                                             \
        int sv = __shfl(idxc, gbase + (LN), 64);                  \
        REG = hb4[(size_t)sv * 8 + c];                            \
    }
#define GIN_CONS(REG, EO)                                         \
    if (e + (EO) < deg) {                                         \
        a0 += lo16(REG.x); a1 += hi16(REG.x);                     \
        a2 += lo16(REG.y); a3 += hi16(REG.y);                     \
        a4 += lo16(REG.z); a5 += hi16(REG.z);                     \
        a6 += lo16(REG.w); a7 += hi16(REG.w);                     \
    }
            // prologue: k = 0,1,2 (padded idx -> row 0 for short groups)
            {
                int e = 0;
                (void)e;
                GIN_ISSUE(v0, 0)
                GIN_ISSUE(v1, 1)
                GIN_ISSUE(v2, 2)
            }
            for (int e = 0; e < steps; e += 8) {
                // invariant: v0,v1,v2 hold steps e,e+1,e+2; idxc=block(e/8),
                // idxn=block(e/8+1)
                GIN_ISSUE(v3, 3) GIN_CONS(v0, 0)   // issue k=e+3
                GIN_ISSUE(v0, 4) GIN_CONS(v1, 1)   // k=e+4
                GIN_ISSUE(v1, 5) GIN_CONS(v2, 2)   // k=e+5
                GIN_ISSUE(v2, 6) GIN_CONS(v3, 3)   // k=e+6
                GIN_ISSUE(v3, 7) GIN_CONS(v0, 4)   // k=e+7
                idxc = idxn;                        // cross to block(e/8+1)
                {
                    int nj = e + 16 + c;
                    idxn = (nj < deg) ? csr_src[beg + nj] : 0;
                }
                GIN_ISSUE(v0, 0) GIN_CONS(v1, 5)   // k=e+8
                GIN_ISSUE(v1, 1) GIN_CONS(v2, 6)   // k=e+9
                GIN_ISSUE(v2, 2) GIN_CONS(v3, 7)   // k=e+10
            }
#undef GIN_ISSUE
#undef GIN_CONS
            // v0..v2 hold 3 tail dummies (row 0); compiler waits before reuse
        }
        if (selff) {
            float4 s0 = selff[(size_t)node * 16 + 2 * c];
            float4 s1 = selff[(size_t)node * 16 + 2 * c + 1];
            a0 += s0.x; a1 += s0.y; a2 += s0.z; a3 += s0.w;
            a4 += s1.x; a5 += s1.y; a6 += s1.z; a7 += s1.w;
        } else {
            uint4 sv = hb4[node * 8 + c];
            a0 += lo16(sv.x); a1 += hi16(sv.x);
            a2 += lo16(sv.y); a3 += hi16(sv.y);
            a4 += lo16(sv.z); a5 += hi16(sv.z);
            a6 += lo16(sv.w); a7 += hi16(sv.w);
        }
        uint4 o;
        o.x = pk(a0, a1); o.y = pk(a2, a3); o.z = pk(a4, a5); o.w = pk(a6, a7);
        *reinterpret_cast<uint4*>(&zl[r * 72 + c * 8]) = o;
    }
    __syncthreads();

    // ---- Phase B: MLP on the 32-row tile (verified round-5 body) ----
    int m = lane & 15;
    int quad = lane >> 4;
    int mt = wv >> 1;  // row half (rows mt*16 + 0..15)
    int nh = wv & 1;   // col half (n-tiles nh*2, nh*2+1)
    int lrow = mt * 16 + m;

    bf16x8 a0 = *reinterpret_cast<const bf16x8*>(&zl[lrow * 72 + quad * 8]);
    bf16x8 a1 = *reinterpret_cast<const bf16x8*>(&zl[lrow * 72 + 32 + quad * 8]);
    const bf16x8* wh1 = reinterpret_cast<const bf16x8*>(wf1);
    const bf16x8* wl1 = reinterpret_cast<const bf16x8*>(wf1 + 4096);
    f32x4 acc[2];
#pragma unroll
    for (int nt2 = 0; nt2 < 2; ++nt2) {
        int n = (nh * 2 + nt2) * 16 + m;
        bf16x8 bh0 = wh1[(0 * 64 + n) * 4 + quad];
        bf16x8 bh1 = wh1[(1 * 64 + n) * 4 + quad];
        bf16x8 bl0 = wl1[(0 * 64 + n) * 4 + quad];
        bf16x8 bl1 = wl1[(1 * 64 + n) * 4 + quad];
        f32x4 c = {0.f, 0.f, 0.f, 0.f};
        c = __builtin_amdgcn_mfma_f32_16x16x32_bf16(a0, bh0, c, 0, 0, 0);
        c = __builtin_amdgcn_mfma_f32_16x16x32_bf16(a1, bh1, c, 0, 0, 0);
        c = __builtin_amdgcn_mfma_f32_16x16x32_bf16(a0, bl0, c, 0, 0, 0);
        c = __builtin_amdgcn_mfma_f32_16x16x32_bf16(a1, bl1, c, 0, 0, 0);
        acc[nt2] = c;
    }
    // h1 = ReLU(acc + b1) -> split bf16 into LDS (C-layout scatter)
#pragma unroll
    for (int nt2 = 0; nt2 < 2; ++nt2) {
        int col = (nh * 2 + nt2) * 16 + m;
        float bb = b1[col];
#pragma unroll
        for (int rr = 0; rr < 4; ++rr) {
            float v = fmaxf(acc[nt2][rr] + bb, 0.f);
            unsigned short hi = f2b(v);
            hlh[(mt * 16 + quad * 4 + rr) * 72 + col] = hi;
            hll[(mt * 16 + quad * 4 + rr) * 72 + col] = f2b(v - b2f(hi));
        }
    }
    __syncthreads();

    // GEMM2: A (hi+lo) from LDS
    bf16x8 ch0 = *reinterpret_cast<const bf16x8*>(&hlh[lrow * 72 + quad * 8]);
    bf16x8 ch1 = *reinterpret_cast<const bf16x8*>(&hlh[lrow * 72 + 32 + quad * 8]);
    bf16x8 cl0 = *reinterpret_cast<const bf16x8*>(&hll[lrow * 72 + quad * 8]);
    bf16x8 cl1 = *reinterpret_cast<const bf16x8*>(&hll[lrow * 72 + 32 + quad * 8]);
    const bf16x8* wh2 = reinterpret_cast<const bf16x8*>(wf2);
    const bf16x8* wl2 = reinterpret_cast<const bf16x8*>(wf2 + 4096);
#pragma unroll
    for (int nt2 = 0; nt2 < 2; ++nt2) {
        int n = (nh * 2 + nt2) * 16 + m;
        bf16x8 bh0 = wh2[(0 * 64 + n) * 4 + quad];
        bf16x8 bh1 = wh2[(1 * 64 + n) * 4 + quad];
        bf16x8 bl0 = wl2[(0 * 64 + n) * 4 + quad];
        bf16x8 bl1 = wl2[(1 * 64 + n) * 4 + quad];
        f32x4 c = {0.f, 0.f, 0.f, 0.f};
        c = __builtin_amdgcn_mfma_f32_16x16x32_bf16(ch0, bh0, c, 0, 0, 0);
        c = __builtin_amdgcn_mfma_f32_16x16x32_bf16(ch1, bh1, c, 0, 0, 0);
        c = __builtin_amdgcn_mfma_f32_16x16x32_bf16(ch0, bl0, c, 0, 0, 0);
        c = __builtin_amdgcn_mfma_f32_16x16x32_bf16(ch1, bl1, c, 0, 0, 0);
        c = __builtin_amdgcn_mfma_f32_16x16x32_bf16(cl0, bh0, c, 0, 0, 0);
        c = __builtin_amdgcn_mfma_f32_16x16x32_bf16(cl1, bh1, c, 0, 0, 0);
        acc[nt2] = c;
    }
    __syncthreads();  // all GEMM2 LDS reads done; hlh/hll reusable

    if (pool_mode) {
        // fused global_add_pool + FC
        float psum[4] = {0.f, 0.f, 0.f, 0.f};
#pragma unroll
        for (int nt2 = 0; nt2 < 2; ++nt2) {
            int col = (nh * 2 + nt2) * 16 + m;
            float fw = fcw[col];
            float bb = b2[col];
#pragma unroll
            for (int rr = 0; rr < 4; ++rr) psum[rr] += (acc[nt2][rr] + bb) * fw;
        }
#pragma unroll
        for (int rr = 0; rr < 4; ++rr)
#pragma unroll
            for (int off = 8; off > 0; off >>= 1)
                psum[rr] += __shfl_down(psum[rr], off, 64);
        float* gsum = reinterpret_cast<float*>(hlh);
        gsum[tid] = 0.f;  // tid 0..255 == graph ids
        __syncthreads();
        if (m == 0) {
#pragma unroll
            for (int rr = 0; rr < 4; ++rr) {
                int row = base + mt * 16 + quad * 4 + rr;
                atomicAdd(&gsum[batch[row]], psum[rr]);
            }
        }
        __syncthreads();
        float v = gsum[tid];
        if (v != 0.f) unsafeAtomicAdd(&outp[tid], v);
        return;
    }

    // epilogue: bias (+relu) -> LDS bf16, then coalesced stores
#pragma unroll
    for (int nt2 = 0; nt2 < 2; ++nt2) {
        int col = (nh * 2 + nt2) * 16 + m;
        float bb = b2[col];
#pragma unroll
        for (int rr = 0; rr < 4; ++rr) {
            float v = acc[nt2][rr] + bb;
            if (relu_out) v = fmaxf(v, 0.f);
            hlh[(mt * 16 + quad * 4 + rr) * 72 + col] = f2b(v);
        }
    }
    __syncthreads();
    {
        int row = tid >> 3;  // 0..31
        int ch = tid & 7;
        uint4 v = *reinterpret_cast<const uint4*>(&hlh[row * 72 + ch * 8]);
        *reinterpret_cast<uint4*>(houtb + (size_t)(base + row) * 64 + ch * 8) = v;
    }
}

extern "C" void kernel_launch(void* const* d_in, const int* in_sizes, int n_in,
                              void* d_out, int out_size, void* d_ws, size_t ws_size,
                              hipStream_t stream) {
    const float* x = (const float*)d_in[0];
    const int* ei = (const int*)d_in[1];     // [2, E] flat
    const int* batch = (const int*)d_in[2];  // [N], sorted
    const float* w[3][4];
    for (int l = 0; l < 3; ++l)
        for (int i = 0; i < 4; ++i) w[l][i] = (const float*)d_in[3 + l * 4 + i];
    const float* fcw = (const float*)d_in[15];
    const float* fcb = (const float*)d_in[16];
    float* out = (float*)d_out;

    // workspace layout (~43 MB), every region 256 B aligned
    char* wsb = (char*)d_ws;
    size_t o = 0;
    auto carve = [&](size_t bytes) {
        char* p = wsb + o;
        o += (bytes + 255) & ~(size_t)255;
        return p;
    };
    int* pairs = (int*)carve((size_t)NEB * EPB * 4);       // 6.4 MB
    int* ocnt = (int*)carve((size_t)NEB * NBKT * 4);       // 0.6 MB
    int* csr = (int*)carve((size_t)NBKT * CAP * 4);        // 9.6 MB
    int* rowptr = (int*)carve((size_t)NN * 4);
    int* degs = (int*)carve((size_t)NN * 4);
    unsigned short* H0 = (unsigned short*)carve((size_t)NN * DD * 2);  // 12.8 MB
    unsigned short* H1 = (unsigned short*)carve((size_t)NN * DD * 2);  // 12.8 MB
    unsigned short* wf = (unsigned short*)carve(6 * 8192 * 2);

    // D1: pscat (no-atomic count matrix) + wconv + out-init + xconv
    build1_k<<<NEB + 7 + XCB, 256, 0, stream>>>(ei, pairs, ocnt, x, H0, w[0][0],
                                                w[0][2], w[1][0], w[1][2],
                                                w[2][0], w[2][2], wf, fcb, out);
    // D2: bucket gather + per-node counting sort -> csr/rowptr/degs
    build2_k<<<NBKT, 256, 0, stream>>>(pairs, ocnt, rowptr, degs, csr);

    dim3 lgrid(NN / 32);
    // D3 L0: read H0(=xb)+x, write H1
    gin_k<<<lgrid, 256, 0, stream>>>((const uint4*)H0, (const float4*)x, rowptr,
                                     degs, csr, wf + 0 * 8192, w[0][1],
                                     wf + 1 * 8192, w[0][3], H1, 1, 0, nullptr,
                                     nullptr, nullptr);
    // D4 L1: read H1, write H0
    gin_k<<<lgrid, 256, 0, stream>>>((const uint4*)H1, nullptr, rowptr, degs,
                                     csr, wf + 2 * 8192, w[1][1], wf + 3 * 8192,
                                     w[1][3], H0, 1, 0, nullptr, nullptr,
                                     nullptr);
    // D5 L2: read H0, fused pool + FC
    gin_k<<<lgrid, 256, 0, stream>>>((const uint4*)H0, nullptr, rowptr, degs,
                                     csr, wf + 4 * 8192, w[2][1], wf + 5 * 8192,
                                     w[2][3], nullptr, 0, 1, batch, fcw, out);
}